// Round 1
// baseline (228.294 us; speedup 1.0000x reference)
//
#include <hip/hip_runtime.h>

// 3x3 'SAME' conv per independent 4x4 tile, masked to nonzero input sites.
// Layout: x flat [N,4,4]; output [N,1,4,4] is flat-identical.
//
// R1 change vs baseline: neighbor rows via direct global re-loads (L1-hit,
// same lines the wave already fetches) instead of 8 ds_bpermute shuffles.
// Removes all LDS-crossbar ops + lgkm waits from the critical path and
// gives 3 independent 16B loads in flight per thread. DRAM traffic is
// unchanged (compulsory 134 MB in + 134 MB out).

typedef float vfloat4 __attribute__((ext_vector_type(4)));

__global__ __launch_bounds__(256) void subm_conv44_row_kernel(
    const float4* __restrict__ x4, const float* __restrict__ W,
    float4* __restrict__ out4, int n_rows)
{
    const int gid = blockIdx.x * blockDim.x + threadIdx.x;
    if (gid >= n_rows) return;

    // This thread owns row r of tile (gid>>2).
    const int r = gid & 3;
    const bool hasU = (r > 0);
    const bool hasD = (r < 3);

    // Three independent coalesced 16B loads, issued back-to-back.
    // u/d addresses are clamped inside the tile (always valid); their
    // values are masked below, so the clamped duplicates are harmless.
    const float4 c  = x4[gid];
    const float4 uu = x4[gid - (hasU ? 1 : 0)];
    const float4 dd = x4[gid + (hasD ? 1 : 0)];

    // 3x3 weight, w[ki*3+kj]; uniform address -> scalar loads.
    float w[9];
#pragma unroll
    for (int i = 0; i < 9; ++i) w[i] = W[i];

    // Zero-padded horizontal windows: idx 0 and 5 are the pad columns.
    float up[6] = {0.f, hasU ? uu.x : 0.f, hasU ? uu.y : 0.f,
                        hasU ? uu.z : 0.f, hasU ? uu.w : 0.f, 0.f};
    float mi[6] = {0.f, c.x, c.y, c.z, c.w, 0.f};
    float dn[6] = {0.f, hasD ? dd.x : 0.f, hasD ? dd.y : 0.f,
                        hasD ? dd.z : 0.f, hasD ? dd.w : 0.f, 0.f};

    vfloat4 o;
#pragma unroll
    for (int j = 0; j < 4; ++j) {
        float acc = 0.0f;
#pragma unroll
        for (int k = 0; k < 3; ++k) {
            acc = fmaf(up[j + k], w[0 * 3 + k], acc);
            acc = fmaf(mi[j + k], w[1 * 3 + k], acc);
            acc = fmaf(dn[j + k], w[2 * 3 + k], acc);
        }
        // Submanifold mask: write only where the input site was nonzero.
        o[j] = (mi[j + 1] != 0.0f) ? acc : 0.0f;
    }

    // Streaming output, never re-read: nontemporal store keeps L2/L3 clean.
    __builtin_nontemporal_store(o, reinterpret_cast<vfloat4*>(&out4[gid]));
}

extern "C" void kernel_launch(void* const* d_in, const int* in_sizes, int n_in,
                              void* d_out, int out_size, void* d_ws, size_t ws_size,
                              hipStream_t stream) {
    const float4* x4 = (const float4*)d_in[0];
    const float*  W  = (const float*)d_in[1];
    float4* out4     = (float4*)d_out;

    const int n_rows = in_sizes[0] / 4;            // one float4 row per thread
    const int block = 256;
    const int grid = (n_rows + block - 1) / block; // 32768 blocks

    subm_conv44_row_kernel<<<grid, block, 0, stream>>>(x4, W, out4, n_rows);
}

// Round 2
// 220.814 us; speedup vs baseline: 1.0339x; 1.0339x over previous
//
#include <hip/hip_runtime.h>

// 3x3 'SAME' conv per independent 4x4 tile, masked to nonzero input sites.
// Layout: x flat [N,4,4]; output [N,1,4,4] is flat-identical.
//
// R2: revert to the R0 memory path (1 coalesced 16B load/lane, NORMAL store
// -- nt store regressed R1 by bypassing L2 write aggregation). Cross-lane
// row exchange now via DPP row-shift moves (single-cycle VALU) instead of
// 8 ds_bpermute ops: no LDS crossbar, no lgkmcnt waits.
//
// DPP validity: tiles are 4 consecutive lanes; row_shr:1/row_shl:1 operate
// within 16-lane rows. Every lane that USES the shifted value (hasU: i&3>=1,
// hasD: i&3<=2) has its source lane in the same 16-lane row AND same tile.
// Row-boundary lanes get bound_ctrl zeros and are masked anyway.

__device__ __forceinline__ float dpp_shr1(float v) {   // lane i <- lane i-1
    return __builtin_bit_cast(float, __builtin_amdgcn_update_dpp(
        0, __builtin_bit_cast(int, v), 0x111 /*row_shr:1*/, 0xf, 0xf, true));
}
__device__ __forceinline__ float dpp_shl1(float v) {   // lane i <- lane i+1
    return __builtin_bit_cast(float, __builtin_amdgcn_update_dpp(
        0, __builtin_bit_cast(int, v), 0x101 /*row_shl:1*/, 0xf, 0xf, true));
}

__global__ __launch_bounds__(256) void subm_conv44_row_kernel(
    const float4* __restrict__ x4, const float* __restrict__ W,
    float4* __restrict__ out4, int n_rows)
{
    const int gid = blockIdx.x * blockDim.x + threadIdx.x;
    if (gid >= n_rows) return;

    // 3x3 weight, w[ki*3+kj]; uniform address -> scalar loads.
    float w[9];
#pragma unroll
    for (int i = 0; i < 9; ++i) w[i] = W[i];

    // This thread owns row r of tile (gid>>2).
    const int r = gid & 3;
    const float4 c = x4[gid];                  // coalesced: 16B/lane contiguous

    // Neighbor rows from adjacent lanes via DPP (tile = 4 consecutive lanes;
    // a tile never straddles a wave or a 16-lane DPP row for the lanes that
    // consume the value).
    float4 u, d;
    u.x = dpp_shr1(c.x);  u.y = dpp_shr1(c.y);
    u.z = dpp_shr1(c.z);  u.w = dpp_shr1(c.w);
    d.x = dpp_shl1(c.x);  d.y = dpp_shl1(c.y);
    d.z = dpp_shl1(c.z);  d.w = dpp_shl1(c.w);

    const bool hasU = (r > 0);
    const bool hasD = (r < 3);

    // Zero-padded horizontal windows: idx 0 and 5 are the pad columns.
    float up[6] = {0.f, hasU ? u.x : 0.f, hasU ? u.y : 0.f,
                        hasU ? u.z : 0.f, hasU ? u.w : 0.f, 0.f};
    float mi[6] = {0.f, c.x, c.y, c.z, c.w, 0.f};
    float dn[6] = {0.f, hasD ? d.x : 0.f, hasD ? d.y : 0.f,
                        hasD ? d.z : 0.f, hasD ? d.w : 0.f, 0.f};

    float4 o;
    float* op = &o.x;
#pragma unroll
    for (int j = 0; j < 4; ++j) {
        float acc = 0.0f;
#pragma unroll
        for (int k = 0; k < 3; ++k) {
            acc = fmaf(up[j + k], w[0 * 3 + k], acc);
            acc = fmaf(mi[j + k], w[1 * 3 + k], acc);
            acc = fmaf(dn[j + k], w[2 * 3 + k], acc);
        }
        // Submanifold mask: write only where the input site was nonzero.
        op[j] = (mi[j + 1] != 0.0f) ? acc : 0.0f;
    }

    out4[gid] = o;                             // coalesced store, normal path
}

extern "C" void kernel_launch(void* const* d_in, const int* in_sizes, int n_in,
                              void* d_out, int out_size, void* d_ws, size_t ws_size,
                              hipStream_t stream) {
    const float4* x4 = (const float4*)d_in[0];
    const float*  W  = (const float*)d_in[1];
    float4* out4     = (float4*)d_out;

    const int n_rows = in_sizes[0] / 4;            // one float4 row per thread
    const int block = 256;
    const int grid = (n_rows + block - 1) / block; // 32768 blocks

    subm_conv44_row_kernel<<<grid, block, 0, stream>>>(x4, W, out4, n_rows);
}